// Round 1
// baseline (398.823 us; speedup 1.0000x reference)
//
#include <hip/hip_runtime.h>

#define D 64          // node/edge feature dim
#define HID 128       // hidden dim
#define MLPB 512      // MLP block size (8 waves)
#define WPB 8         // waves per block
#define NB 4          // nodes per wave-batch

// ---------------------------------------------------------------------------
// Scatter: agg[src[e]] += x_edge[e]; agg[dst[e]] += x_edge[e]
// One wave per edge (lane = feature dim). Coalesced 256B reads per edge row.
// f32 hardware atomics via unsafeAtomicAdd (global_atomic_add_f32).
// Index dtype (int32 vs int64-as-int-pairs) detected per-wave, deterministic.
// ---------------------------------------------------------------------------
__global__ __launch_bounds__(256)
void nb_scatter(const float* __restrict__ x_edge, const int* __restrict__ eidx,
                float* __restrict__ agg, int n_edges)
{
    long long t = (long long)blockIdx.x * 256 + threadIdx.x;
    int e = (int)(t >> 6);
    if (e >= n_edges) return;
    int d = (int)(t & 63);

    // Detect int64 layout: low/high word pairs, high words all zero.
    // For int32 data these probed words are random src values in [0,50000):
    // P(all 64 are zero) ~ (2e-5)^64 ~ 0.
    int probe = eidx[2 * (threadIdx.x & 63) + 1];
    bool is64 = (__ballot(probe == 0) == ~0ULL);

    int s, dd;
    if (is64) {
        s  = eidx[2 * (size_t)e];
        dd = eidx[2 * ((size_t)n_edges + (size_t)e)];
    } else {
        s  = eidx[e];
        dd = eidx[n_edges + e];
    }

    float v = x_edge[(size_t)e * D + d];
    unsafeAtomicAdd(&agg[(size_t)s * D + d], v);
    unsafeAtomicAdd(&agg[(size_t)dd * D + d], v);
}

// ---------------------------------------------------------------------------
// MLP: out[n] = relu(concat(x_node[n], agg[n]) @ W1 + b1) @ W2 + b2
// W1 (64KB) + W2 (32KB) staged in LDS once per block.
// One wave processes NB=4 nodes at a time: lane j owns hidden units 2j,2j+1,
// inputs staged as float4-over-nodes so each weight read feeds 4 nodes
// (8 FMAs per 8B W1 read). agg is read from d_out and out written in place
// (row n is read and written only by its own wave).
// ---------------------------------------------------------------------------
__global__ __launch_bounds__(MLPB, 1)
void nb_mlp(const float* __restrict__ x_node, const float* __restrict__ agg,
            const float* __restrict__ W1, const float* __restrict__ b1,
            const float* __restrict__ W2, const float* __restrict__ b2,
            float* __restrict__ out, int n_nodes)
{
    __shared__ float sW1[HID * HID];     // 64 KB, W1[k][j] row-major
    __shared__ float sW2[HID * D];       // 32 KB, W2[h][j] row-major
    __shared__ float sb1[HID];
    __shared__ float sb2[D];
    __shared__ float4 s_in[WPB][128];    // [k] x float4 over 4 nodes
    __shared__ float4 s_h[WPB][128];     // [h] x float4 over 4 nodes

    {
        const float4* W14 = (const float4*)W1;
        float4* sW14 = (float4*)sW1;
        #pragma unroll
        for (int i = 0; i < 8; ++i)
            sW14[threadIdx.x + i * MLPB] = W14[threadIdx.x + i * MLPB];
        const float4* W24 = (const float4*)W2;
        float4* sW24 = (float4*)sW2;
        #pragma unroll
        for (int i = 0; i < 4; ++i)
            sW24[threadIdx.x + i * MLPB] = W24[threadIdx.x + i * MLPB];
        if (threadIdx.x < 128) sb1[threadIdx.x] = b1[threadIdx.x];
        else if (threadIdx.x < 192) sb2[threadIdx.x - 128] = b2[threadIdx.x - 128];
    }
    __syncthreads();

    const int wave = threadIdx.x >> 6;
    const int lane = threadIdx.x & 63;
    const int group = blockIdx.x * WPB + wave;
    const int ngroups = gridDim.x * WPB;
    const int nbatches = (n_nodes + NB - 1) / NB;
    const float2* sW1_2 = (const float2*)sW1;

    for (int g = group; g < nbatches; g += ngroups) {
        const int n0 = g * NB;

        // ---- stage inputs: lane j provides k=j (x_node) and k=64+j (agg) ----
        float4 vx, va;
        #pragma unroll
        for (int b = 0; b < NB; ++b) {
            const int n = n0 + b;
            const bool ok = (n < n_nodes);
            ((float*)&vx)[b] = ok ? x_node[(size_t)n * D + lane] : 0.f;
            ((float*)&va)[b] = ok ? agg[(size_t)n * D + lane] : 0.f;
        }
        s_in[wave][lane] = vx;
        s_in[wave][64 + lane] = va;
        __builtin_amdgcn_wave_barrier();   // wave-local LDS: keep program order

        // ---- hidden layer: lane j -> hidden units 2j, 2j+1 for 4 nodes ----
        const float bh0 = sb1[2 * lane], bh1 = sb1[2 * lane + 1];
        float a0[NB], a1[NB];
        #pragma unroll
        for (int b = 0; b < NB; ++b) { a0[b] = bh0; a1[b] = bh1; }

        #pragma unroll 4
        for (int k = 0; k < 128; ++k) {
            const float4 a = s_in[wave][k];          // broadcast, 4 nodes
            const float2 w = sW1_2[k * 64 + lane];   // W1[k][2j], W1[k][2j+1]
            #pragma unroll
            for (int b = 0; b < NB; ++b) {
                a0[b] = fmaf(((const float*)&a)[b], w.x, a0[b]);
                a1[b] = fmaf(((const float*)&a)[b], w.y, a1[b]);
            }
        }
        float4 h0v, h1v;
        #pragma unroll
        for (int b = 0; b < NB; ++b) {
            ((float*)&h0v)[b] = fmaxf(a0[b], 0.f);
            ((float*)&h1v)[b] = fmaxf(a1[b], 0.f);
        }
        s_h[wave][2 * lane]     = h0v;
        s_h[wave][2 * lane + 1] = h1v;
        __builtin_amdgcn_wave_barrier();

        // ---- output layer: lane j -> out[j] for 4 nodes ----
        const float bo = sb2[lane];
        float o[NB];
        #pragma unroll
        for (int b = 0; b < NB; ++b) o[b] = bo;
        #pragma unroll 4
        for (int hh = 0; hh < 128; ++hh) {
            const float4 hv = s_h[wave][hh];         // broadcast, 4 nodes
            const float wv = sW2[hh * 64 + lane];    // W2[h][j]
            #pragma unroll
            for (int b = 0; b < NB; ++b)
                o[b] = fmaf(((const float*)&hv)[b], wv, o[b]);
        }
        #pragma unroll
        for (int b = 0; b < NB; ++b) {
            const int n = n0 + b;
            if (n < n_nodes) out[(size_t)n * D + lane] = o[b];
        }
    }
}

// ---------------------------------------------------------------------------
extern "C" void kernel_launch(void* const* d_in, const int* in_sizes, int n_in,
                              void* d_out, int out_size, void* d_ws, size_t ws_size,
                              hipStream_t stream)
{
    const float* x_node = (const float*)d_in[0];
    const float* x_edge = (const float*)d_in[1];
    const int*   eidx   = (const int*)d_in[2];
    const float* W1     = (const float*)d_in[3];
    const float* b1     = (const float*)d_in[4];
    const float* W2     = (const float*)d_in[5];
    const float* b2     = (const float*)d_in[6];
    float* out = (float*)d_out;

    const int n_nodes = in_sizes[0] / D;     // 50000
    const int n_edges = in_sizes[2] / 2;     // 800000

    // agg lives in d_out (exactly n_nodes*64 floats); MLP then rewrites
    // each row in place after its own wave has consumed it.
    float* agg = out;
    hipMemsetAsync(agg, 0, (size_t)n_nodes * D * sizeof(float), stream);

    {
        long long threads = (long long)n_edges * 64;
        int blocks = (int)((threads + 255) / 256);
        nb_scatter<<<blocks, 256, 0, stream>>>(x_edge, eidx, agg, n_edges);
    }

    nb_mlp<<<256, MLPB, 0, stream>>>(x_node, agg, W1, b1, W2, b2, out, n_nodes);
}

// Round 2
// 355.928 us; speedup vs baseline: 1.1205x; 1.1205x over previous
//
#include <hip/hip_runtime.h>

#define D 64          // node/edge feature dim
#define HID 128       // hidden dim
#define MLPB 512      // MLP block size (8 waves)
#define WPB 8         // waves per block
#define NB 4          // nodes per wave-batch

// ---------------------------------------------------------------------------
// Index dtype note: reference declares edge_index int64; harness may deliver
// int32. Detect per-wave: probe high words of the first 64 pairs — for int64
// they are all 0 (indices < 50000); for int32 they are random node ids,
// P(all 64 == 0) ~ (2e-5)^64 ~ 0. Deterministic given the input.
// ---------------------------------------------------------------------------
__device__ __forceinline__ bool detect_i64(const int* __restrict__ eidx, int lane)
{
    int probe = eidx[2 * lane + 1];
    return (__ballot(probe == 0) == ~0ULL);
}

// ---------- CSR build ------------------------------------------------------
// Entry t in [0, 2E): t < E -> src of edge t; t >= E -> dst of edge t-E.
__global__ __launch_bounds__(256)
void csr_hist(const int* __restrict__ eidx, int* __restrict__ counts, int n_edges)
{
    int t = blockIdx.x * 256 + threadIdx.x;
    bool is64 = detect_i64(eidx, threadIdx.x & 63);
    if (t >= 2 * n_edges) return;
    int idx = is64 ? eidx[2 * (size_t)t] : eidx[t];
    atomicAdd(&counts[idx], 1);
}

__global__ __launch_bounds__(256)
void csr_blocksum(const int* __restrict__ counts, int* __restrict__ bsum, int n)
{
    int i = blockIdx.x * 256 + threadIdx.x;
    int v = (i < n) ? counts[i] : 0;
    #pragma unroll
    for (int o = 1; o < 64; o <<= 1) v += __shfl_xor(v, o);
    __shared__ int ws[4];
    if ((threadIdx.x & 63) == 0) ws[threadIdx.x >> 6] = v;
    __syncthreads();
    if (threadIdx.x == 0) bsum[blockIdx.x] = ws[0] + ws[1] + ws[2] + ws[3];
}

__global__ __launch_bounds__(256)
void csr_scan_bsum(int* __restrict__ bsum, int nb)
{
    __shared__ int s[256];
    int i = threadIdx.x;
    int v = (i < nb) ? bsum[i] : 0;
    s[i] = v; __syncthreads();
    #pragma unroll
    for (int o = 1; o < 256; o <<= 1) {
        int t = (i >= o) ? s[i - o] : 0;
        __syncthreads();
        s[i] += t;
        __syncthreads();
    }
    if (i < nb) bsum[i] = s[i] - v;   // exclusive
}

__global__ __launch_bounds__(256)
void csr_scan_final(const int* __restrict__ counts, const int* __restrict__ bsum,
                    int* __restrict__ offsets, int* __restrict__ cursor, int n)
{
    __shared__ int s[256];
    int i = blockIdx.x * 256 + threadIdx.x;
    int v = (i < n) ? counts[i] : 0;
    s[threadIdx.x] = v; __syncthreads();
    #pragma unroll
    for (int o = 1; o < 256; o <<= 1) {
        int t = (threadIdx.x >= o) ? s[threadIdx.x - o] : 0;
        __syncthreads();
        s[threadIdx.x] += t;
        __syncthreads();
    }
    int excl = s[threadIdx.x] - v + bsum[blockIdx.x];
    if (i < n) { offsets[i] = excl; cursor[i] = excl; }
    if (i == n - 1) offsets[n] = excl + v;   // total = 2E
}

__global__ __launch_bounds__(256)
void csr_place(const int* __restrict__ eidx, int* __restrict__ cursor,
               int* __restrict__ elist, int n_edges)
{
    int t = blockIdx.x * 256 + threadIdx.x;
    bool is64 = detect_i64(eidx, threadIdx.x & 63);
    if (t >= 2 * n_edges) return;
    int idx = is64 ? eidx[2 * (size_t)t] : eidx[t];
    int eid = (t < n_edges) ? t : t - n_edges;
    int p = atomicAdd(&cursor[idx], 1);
    elist[p] = eid;
}

// ---------- gather: agg[n] = sum over incident edges of x_edge[e] ----------
// One wave per node; lane = feature dim. Each edge row read is 256B
// contiguous (4 full cache lines). 4-deep unroll for memory-level parallelism.
__global__ __launch_bounds__(256)
void csr_gather(const float* __restrict__ x_edge, const int* __restrict__ offsets,
                const int* __restrict__ elist, float* __restrict__ agg, int n_nodes)
{
    int w = (blockIdx.x * 256 + threadIdx.x) >> 6;
    int lane = threadIdx.x & 63;
    if (w >= n_nodes) return;
    int beg = offsets[w], end = offsets[w + 1];
    float acc = 0.f;
    int i = beg;
    for (; i + 4 <= end; i += 4) {
        int e0 = elist[i], e1 = elist[i + 1], e2 = elist[i + 2], e3 = elist[i + 3];
        float v0 = x_edge[(size_t)e0 * D + lane];
        float v1 = x_edge[(size_t)e1 * D + lane];
        float v2 = x_edge[(size_t)e2 * D + lane];
        float v3 = x_edge[(size_t)e3 * D + lane];
        acc += v0 + v1 + v2 + v3;
    }
    for (; i < end; ++i) acc += x_edge[(size_t)elist[i] * D + lane];
    agg[(size_t)w * D + lane] = acc;
}

// ---------- fallback atomic scatter (used only if ws too small) ------------
__global__ __launch_bounds__(256)
void nb_scatter(const float* __restrict__ x_edge, const int* __restrict__ eidx,
                float* __restrict__ agg, int n_edges)
{
    long long t = (long long)blockIdx.x * 256 + threadIdx.x;
    int e = (int)(t >> 6);
    if (e >= n_edges) return;
    int d = (int)(t & 63);
    bool is64 = detect_i64(eidx, threadIdx.x & 63);
    int s, dd;
    if (is64) {
        s  = eidx[2 * (size_t)e];
        dd = eidx[2 * ((size_t)n_edges + (size_t)e)];
    } else {
        s  = eidx[e];
        dd = eidx[n_edges + e];
    }
    float v = x_edge[(size_t)e * D + d];
    unsafeAtomicAdd(&agg[(size_t)s * D + d], v);
    unsafeAtomicAdd(&agg[(size_t)dd * D + d], v);
}

// ---------------------------------------------------------------------------
// MLP: out[n] = relu(concat(x_node[n], agg[n]) @ W1 + b1) @ W2 + b2
// W1 (64KB) + W2 (32KB) staged in LDS once per block. One wave per 4 nodes;
// inputs staged as float4-over-nodes so each weight read feeds 4 nodes.
// agg read from d_out, out written in place (row n touched only by its wave).
// ---------------------------------------------------------------------------
__global__ __launch_bounds__(MLPB, 1)
void nb_mlp(const float* __restrict__ x_node, const float* __restrict__ agg,
            const float* __restrict__ W1, const float* __restrict__ b1,
            const float* __restrict__ W2, const float* __restrict__ b2,
            float* __restrict__ out, int n_nodes)
{
    __shared__ float sW1[HID * HID];
    __shared__ float sW2[HID * D];
    __shared__ float sb1[HID];
    __shared__ float sb2[D];
    __shared__ float4 s_in[WPB][128];
    __shared__ float4 s_h[WPB][128];

    {
        const float4* W14 = (const float4*)W1;
        float4* sW14 = (float4*)sW1;
        #pragma unroll
        for (int i = 0; i < 8; ++i)
            sW14[threadIdx.x + i * MLPB] = W14[threadIdx.x + i * MLPB];
        const float4* W24 = (const float4*)W2;
        float4* sW24 = (float4*)sW2;
        #pragma unroll
        for (int i = 0; i < 4; ++i)
            sW24[threadIdx.x + i * MLPB] = W24[threadIdx.x + i * MLPB];
        if (threadIdx.x < 128) sb1[threadIdx.x] = b1[threadIdx.x];
        else if (threadIdx.x < 192) sb2[threadIdx.x - 128] = b2[threadIdx.x - 128];
    }
    __syncthreads();

    const int wave = threadIdx.x >> 6;
    const int lane = threadIdx.x & 63;
    const int group = blockIdx.x * WPB + wave;
    const int ngroups = gridDim.x * WPB;
    const int nbatches = (n_nodes + NB - 1) / NB;
    const float2* sW1_2 = (const float2*)sW1;

    for (int g = group; g < nbatches; g += ngroups) {
        const int n0 = g * NB;

        float4 vx, va;
        #pragma unroll
        for (int b = 0; b < NB; ++b) {
            const int n = n0 + b;
            const bool ok = (n < n_nodes);
            ((float*)&vx)[b] = ok ? x_node[(size_t)n * D + lane] : 0.f;
            ((float*)&va)[b] = ok ? agg[(size_t)n * D + lane] : 0.f;
        }
        s_in[wave][lane] = vx;
        s_in[wave][64 + lane] = va;
        __builtin_amdgcn_wave_barrier();

        const float bh0 = sb1[2 * lane], bh1 = sb1[2 * lane + 1];
        float a0[NB], a1[NB];
        #pragma unroll
        for (int b = 0; b < NB; ++b) { a0[b] = bh0; a1[b] = bh1; }

        #pragma unroll 4
        for (int k = 0; k < 128; ++k) {
            const float4 a = s_in[wave][k];
            const float2 w = sW1_2[k * 64 + lane];
            #pragma unroll
            for (int b = 0; b < NB; ++b) {
                a0[b] = fmaf(((const float*)&a)[b], w.x, a0[b]);
                a1[b] = fmaf(((const float*)&a)[b], w.y, a1[b]);
            }
        }
        float4 h0v, h1v;
        #pragma unroll
        for (int b = 0; b < NB; ++b) {
            ((float*)&h0v)[b] = fmaxf(a0[b], 0.f);
            ((float*)&h1v)[b] = fmaxf(a1[b], 0.f);
        }
        s_h[wave][2 * lane]     = h0v;
        s_h[wave][2 * lane + 1] = h1v;
        __builtin_amdgcn_wave_barrier();

        const float bo = sb2[lane];
        float o[NB];
        #pragma unroll
        for (int b = 0; b < NB; ++b) o[b] = bo;
        #pragma unroll 4
        for (int hh = 0; hh < 128; ++hh) {
            const float4 hv = s_h[wave][hh];
            const float wv = sW2[hh * 64 + lane];
            #pragma unroll
            for (int b = 0; b < NB; ++b)
                o[b] = fmaf(((const float*)&hv)[b], wv, o[b]);
        }
        #pragma unroll
        for (int b = 0; b < NB; ++b) {
            const int n = n0 + b;
            if (n < n_nodes) out[(size_t)n * D + lane] = o[b];
        }
    }
}

// ---------------------------------------------------------------------------
extern "C" void kernel_launch(void* const* d_in, const int* in_sizes, int n_in,
                              void* d_out, int out_size, void* d_ws, size_t ws_size,
                              hipStream_t stream)
{
    const float* x_node = (const float*)d_in[0];
    const float* x_edge = (const float*)d_in[1];
    const int*   eidx   = (const int*)d_in[2];
    const float* W1     = (const float*)d_in[3];
    const float* b1     = (const float*)d_in[4];
    const float* W2     = (const float*)d_in[5];
    const float* b2     = (const float*)d_in[6];
    float* out = (float*)d_out;

    const int n_nodes = in_sizes[0] / D;     // 50000
    const int n_edges = in_sizes[2] / 2;     // 800000
    const int E2 = 2 * n_edges;

    float* agg = out;   // agg lives in d_out; MLP rewrites rows in place

    // ws layout: offsets[N+1] | counts[N] | cursor[N] | bsum[256] | elist[2E]
    const size_t need = ((size_t)(n_nodes + 1) + n_nodes + n_nodes + 256 + E2) * 4;

    if (ws_size >= need) {
        int* offsets = (int*)d_ws;
        int* counts  = offsets + (n_nodes + 1);
        int* cursor  = counts + n_nodes;
        int* bsum    = cursor + n_nodes;
        int* elist   = bsum + 256;

        const int nscan = (n_nodes + 255) / 256;            // 196 blocks

        hipMemsetAsync(counts, 0, (size_t)n_nodes * 4, stream);
        csr_hist<<<(E2 + 255) / 256, 256, 0, stream>>>(eidx, counts, n_edges);
        csr_blocksum<<<nscan, 256, 0, stream>>>(counts, bsum, n_nodes);
        csr_scan_bsum<<<1, 256, 0, stream>>>(bsum, nscan);
        csr_scan_final<<<nscan, 256, 0, stream>>>(counts, bsum, offsets, cursor, n_nodes);
        csr_place<<<(E2 + 255) / 256, 256, 0, stream>>>(eidx, cursor, elist, n_edges);
        csr_gather<<<(n_nodes * 64 + 255) / 256, 256, 0, stream>>>(
            x_edge, offsets, elist, agg, n_nodes);
    } else {
        hipMemsetAsync(agg, 0, (size_t)n_nodes * D * sizeof(float), stream);
        long long threads = (long long)n_edges * 64;
        nb_scatter<<<(int)((threads + 255) / 256), 256, 0, stream>>>(
            x_edge, eidx, agg, n_edges);
    }

    nb_mlp<<<256, MLPB, 0, stream>>>(x_node, agg, W1, b1, W2, b2, out, n_nodes);
}